// Round 8
// baseline (343.075 us; speedup 1.0000x reference)
//
#include <hip/hip_runtime.h>

// out = min_co( conv2d(x, W, SAME) ) * 2
// x (32,64,128,128) fp32, W (128,64,3,3) fp32 -> out (32,1,128,128) fp32
//
// Round 12: two-pass. R11 post-mortem: stage (12.8k cyc) serializes with
// compute (11k) per block; MFMA floor is 89k cyc/CU but we spend 312k.
// Reg-staging can't overlap (64-VGPR wall, R7/R8/R10). Fix: materialize a
// bf16 pre-swizzled image of x once (prep_x, BW-bound), then the consumer
// stages via global_load_lds (zero registers, linear dest) into a 6-slot
// LDS ring, issuing next tile's loads BEFORE the K-loop -> HBM latency
// hides under ~11k cyc of MFMA (T3/T4/T14).
//   * conv_main: grid 256 (1 block/CU), 512 thr, launch_bounds(512,2)
//     -> 256 VGPR/wave: B 1-deep prefetch finally fits (R5/R11 lesson:
//     B-load latency exposure governs MfmaUtil).
//   * K-loop/epilogue numerics = R11 verbatim (verified absmax 0.0625).
//   * adaptive: ws >= 65 MB ? two-pass : R11 single-pass : direct conv.

typedef __attribute__((ext_vector_type(8)))  short short8;   // 8 x bf16
typedef __attribute__((ext_vector_type(4)))  float float4v;

#define CI 64
#define CO 128
#define HH 128
#define WW 128
#define WP 130

#define WT_BYTES ((size_t)9 * CO * CI * 2)        // 147,456
#define XT_ROW   16384                            // bytes per image row
#define XT_ROWS  130                              // h = -1 .. 128 baked
#define XT_BYTES ((size_t)32 * XT_ROWS * XT_ROW)  // 68,157,440
#define SLOT     16640                            // ring slot: [wp 0..129][128B]

__device__ __forceinline__ unsigned short f2bf(float f) {
    unsigned int u = __float_as_uint(f);
    u = (u + 0x7fffu + ((u >> 16) & 1u)) >> 16;   // RNE
    return (unsigned short)u;
}

template <int CTRL>
__device__ __forceinline__ float fminror(float v) {
    int t = __builtin_amdgcn_mov_dpp(__float_as_int(v), CTRL, 0xF, 0xF, false);
    return fminf(v, __int_as_float(t));
}

typedef __attribute__((address_space(1))) const void gas_void;
typedef __attribute__((address_space(3))) void       las_void;
__device__ __forceinline__ void stage16(const void* g, void* l) {
    // dest = uniform LDS base + lane*16 (HW); src per-lane. 1 KB / wave-call.
    __builtin_amdgcn_global_load_lds((gas_void*)g, (las_void*)l, 16, 0, 0);
}

// ---- prep_w: W (co,ci,3,3) fp32 -> wt2[tap][kc][co][cik] bf16 -------------

__global__ __launch_bounds__(256) void prep_w(
    const float* __restrict__ Wsrc, unsigned short* __restrict__ wt)
{
    int idx = blockIdx.x * 256 + threadIdx.x;          // (tap, co, ci)
    if (idx >= 9 * CO * CI) return;
    int ci  = idx & 63;
    int t   = idx >> 6;
    int co  = t & 127;
    int tap = t >> 7;
    int kc  = ci >> 5;
    int cik = ci & 31;
    wt[(((size_t)tap * 2 + kc) * CO + co) * 32 + cik] =
        f2bf(Wsrc[((size_t)co * CI + ci) * 9 + tap]);
}

// ---- prep_x: x fp32 NCHW -> xt bf16 swizzled row image --------------------
// xt row image byte = (wp-1)*128 + ((ci>>3)^(wp&7))*16 + (ci&7)*2, wp=w+1.
// Loaded linearly into LDS at slot_base+128 it reproduces the exact layout
// the (verified) K-loop reads. Rows 0 and 129 are zeros (h=-1,128).

__global__ __launch_bounds__(256) void prep_x(
    const float* __restrict__ x, unsigned short* __restrict__ xt)
{
    __shared__ __align__(16) char ldsR[XT_ROW];
    const int hp  = blockIdx.x;            // xt row 0..129
    const int b   = blockIdx.y;
    const int tid = threadIdx.x;
    char* dst = (char*)xt + ((size_t)b * XT_ROWS + hp) * XT_ROW;

    if (hp == 0 || hp == XT_ROWS - 1) {
        float4v z = {0.f, 0.f, 0.f, 0.f};
        #pragma unroll
        for (int i = 0; i < 4; ++i)
            *(float4v*)(dst + (tid + 256 * i) * 16) = z;
        return;
    }
    const int h    = hp - 1;
    const int wv   = tid >> 6;             // 0..3 : ci-pair high
    const int lane = tid & 63;
    const int hi   = lane >> 5;
    const int cpl  = (lane >> 2) & 7;
    const int qlo  = (lane & 3) + 4 * hi;  // 0..7
    const int ci0  = 2 * (cpl + 8 * wv);   // 0..62
    #pragma unroll
    for (int qi = 0; qi < 4; ++qi) {
        const int Q = qlo + 8 * qi;        // 0..31
        const float* p0 = x + (((size_t)b * CI + ci0) * HH + h) * WW + Q * 4;
        float4v a0 = *(const float4v*)p0;
        float4v a1 = *(const float4v*)(p0 + (size_t)HH * WW);
        #pragma unroll
        for (int e = 0; e < 4; ++e) {
            const int wp   = Q * 4 + e + 1;           // 1..128
            const int slot = (ci0 >> 3) ^ (wp & 7);
            unsigned int pack;                        // lo=ci0, hi=ci0+1
            asm("v_cvt_pk_bf16_f32 %0, %1, %2"
                : "=v"(pack) : "v"(a0[e]), "v"(a1[e]));
            *(unsigned int*)(ldsR + (size_t)(wp - 1) * 128
                             + slot * 16 + (ci0 & 7) * 2) = pack;
        }
    }
    __syncthreads();
    #pragma unroll
    for (int i = 0; i < 4; ++i) {
        const int c = tid + 256 * i;       // 1024 x 16B = 16384
        *(float4v*)(dst + c * 16) = ((float4v*)ldsR)[c];
    }
}

// ---- conv_main: strip consumer, async ring staging ------------------------

__global__ __launch_bounds__(512, 2) void conv_main(
    const unsigned short* __restrict__ xt,
    const unsigned short* __restrict__ wt,
    float* __restrict__ out)
{
    __shared__ __align__(16) char  ldsA[6 * SLOT];   // 99,840
    __shared__ float scratch[2][2][128];

    const int gid   = blockIdx.x;          // 0..255 -> 1 block/CU
    const int strip = gid & 7;
    const int b     = gid >> 3;
    const int base  = strip * 16;          // first output row of strip

    const int tid  = threadIdx.x;
    const int wid  = tid >> 6;
    const int lane = tid & 63;
    const int l15  = lane & 15;
    const int quad = lane >> 4;
    const int wm   = wid & 1;              // output row of the pair
    const int ms   = (wid >> 1) & 1;       // pixel col half
    const int wn   = wid >> 2;             // co half
    const int n0   = wn * 64;
    const int cb   = ms * 64;

    const char* xb = (const char*)xt + ((size_t)b * XT_ROWS + base) * XT_ROW;

    // ---- zero pad columns (wp = 0, 129) of all 6 ring slots (static) ----
    if (tid < 96) {
        int s   = tid >> 4;                // slot 0..5
        int wp  = ((tid >> 3) & 1) ? 129 : 0;
        int c8  = tid & 7;
        float4v z = {0.f, 0.f, 0.f, 0.f};
        *(float4v*)(ldsA + (size_t)s * SLOT + wp * 128 + c8 * 16) = z;
    }

    // ---- prologue: stage rows lr 0..3 into slots lr%6 (64 wave-calls) ----
    #pragma unroll
    for (int k = 0; k < 8; ++k) {
        const int c   = wid * 8 + k;       // 0..63
        const int lr  = c >> 4;            // 0..3
        const int off = (c & 15) * 1024;
        stage16(xb + (size_t)lr * XT_ROW + off + lane * 16,
                ldsA + (size_t)lr * SLOT + 128 + off);
    }

    // ---- per-lane constants ----
    int aaddr[6];                          // (dw,kc) within-slot offsets
    #pragma unroll
    for (int dw = 0; dw < 3; ++dw) {
        const int key = (dw + l15) & 7;
        #pragma unroll
        for (int kc = 0; kc < 2; ++kc)
            aaddr[dw * 2 + kc] = (dw + cb + l15) * 128
                               + (((kc * 4 + quad) ^ key) << 4);
    }
    const unsigned short* wl = wt + (n0 + l15) * 32 + quad * 8;

    __syncthreads();                       // drains vmcnt: rows 0..3 ready

    // ---- tile loop: 8 tiles of 2 output rows ----
    #pragma unroll 1
    for (int t = 0; t < 8; ++t) {
        // issue async stage of rows 2t+4, 2t+5 (lands during K-loop;
        // published by the epilogue barrier's vmcnt drain)
        if (t < 7) {
            #pragma unroll
            for (int k = 0; k < 4; ++k) {
                const int c   = wid * 4 + k;       // 0..31
                const int lr  = 2 * t + 4 + (c >> 4);
                const int off = (c & 15) * 1024;
                stage16(xb + (size_t)lr * XT_ROW + off + lane * 16,
                        ldsA + (size_t)(lr % 6) * SLOT + 128 + off);
            }
        }
        // ring bases for this tile's 3 tap-rows
        const char* ab[3];
        #pragma unroll
        for (int dh = 0; dh < 3; ++dh)
            ab[dh] = ldsA + (size_t)((2 * t + wm + dh) % 6) * SLOT;

        float4v acc[4][4];
        #pragma unroll
        for (int mt = 0; mt < 4; ++mt)
            #pragma unroll
            for (int nt = 0; nt < 4; ++nt)
                acc[mt][nt] = (float4v){0.f, 0.f, 0.f, 0.f};

        short8 bcur[4], bnxt[4];
        #pragma unroll
        for (int nt = 0; nt < 4; ++nt)
            bcur[nt] = *(const short8*)(wl + nt * 16 * 32);

        #pragma unroll
        for (int it = 0; it < 18; ++it) {
            const int tap = it >> 1;
            const int kc  = it & 1;
            const int dh  = tap / 3;
            const int dw  = tap % 3;

            if (it < 17) {                 // B prefetch 1-deep (regs free now)
                const unsigned short* bp = wl + (size_t)(it + 1) * (CO * 32);
                #pragma unroll
                for (int nt = 0; nt < 4; ++nt)
                    bnxt[nt] = *(const short8*)(bp + nt * 16 * 32);
            }

            const char* abase = ab[dh] + aaddr[dw * 2 + kc];
            short8 af[4];
            #pragma unroll
            for (int mt = 0; mt < 4; ++mt)
                af[mt] = *(const short8*)(abase + mt * 2048);

            __builtin_amdgcn_s_setprio(1);
            #pragma unroll
            for (int mt = 0; mt < 4; ++mt)
                #pragma unroll
                for (int nt = 0; nt < 4; ++nt)
                    acc[mt][nt] = __builtin_amdgcn_mfma_f32_16x16x32_bf16(
                        af[mt], bcur[nt], acc[mt][nt], 0, 0, 0);
            __builtin_amdgcn_s_setprio(0);

            #pragma unroll
            for (int nt = 0; nt < 4; ++nt)
                bcur[nt] = bnxt[nt];
        }

        // ---- epilogue: min over co (R11 verbatim) ----
        float pm[4][4];
        #pragma unroll
        for (int mt = 0; mt < 4; ++mt)
            #pragma unroll
            for (int reg = 0; reg < 4; ++reg)
                pm[mt][reg] = fminf(fminf(acc[mt][0][reg], acc[mt][1][reg]),
                                    fminf(acc[mt][2][reg], acc[mt][3][reg]));
        #pragma unroll
        for (int mt = 0; mt < 4; ++mt)
            #pragma unroll
            for (int reg = 0; reg < 4; ++reg) {
                pm[mt][reg] = fminror<0x128>(pm[mt][reg]);   // row_ror:8
                pm[mt][reg] = fminror<0x124>(pm[mt][reg]);   // row_ror:4
                pm[mt][reg] = fminror<0x122>(pm[mt][reg]);   // row_ror:2
                pm[mt][reg] = fminror<0x121>(pm[mt][reg]);   // row_ror:1
            }
        if (l15 == 0) {
            #pragma unroll
            for (int mt = 0; mt < 4; ++mt)
                #pragma unroll
                for (int reg = 0; reg < 4; ++reg)
                    scratch[wn][wm][cb + mt * 16 + quad * 4 + reg] = pm[mt][reg];
        }
        __syncthreads();     // drains vmcnt (ring t+1 published) + scratch
        if (tid < 256) {
            int r = tid >> 7, c = tid & 127;
            float v = fminf(scratch[0][r][c], scratch[1][r][c]) * 2.0f;
            out[((size_t)b * HH + base + 2 * t + r) * WW + c] = v;
        }
        __syncthreads();     // scratch reusable; ring slots safe to reuse
    }
}

// ---- R11 single-pass path (mid fallback, verified 261 us harness) ---------

#define LDSA_BYTES (4 * WP * CI * 2)   // 66,560

__global__ __launch_bounds__(512, 4) void conv_fused(
    const float* __restrict__ x,
    const unsigned short* __restrict__ wt,
    float* __restrict__ out)
{
    __shared__ __align__(16) char  ldsA[LDSA_BYTES];
    __shared__ float scratch[2][2][128];

    const int bx   = blockIdx.x;
    const int b    = blockIdx.y;
    const int tid  = threadIdx.x;
    const int wid  = tid >> 6;
    const int lane = tid & 63;
    const int l15  = lane & 15;
    const int quad = lane >> 4;
    const int hi   = lane >> 5;
    const int wm   = wid & 1;
    const int ms   = (wid >> 1) & 1;
    const int wn   = wid >> 2;
    const int n0   = wn * 64;
    const int cb   = ms * 64;

    if (tid < 64) {
        int r    = tid >> 4;
        int wp   = ((tid >> 3) & 1) ? 129 : 0;
        int slot = tid & 7;
        float4v z = {0.f, 0.f, 0.f, 0.f};
        *(float4v*)(ldsA + ((size_t)(r * WP + wp) * 128) + slot * 16) = z;
    }
    if (bx == 0) {
        float4v z = {0.f, 0.f, 0.f, 0.f};
        for (int i = tid; i < WP * CI * 2 / 16; i += 512)
            ((float4v*)ldsA)[i] = z;
    }
    if (bx == HH / 2 - 1) {
        float4v z = {0.f, 0.f, 0.f, 0.f};
        for (int i = tid; i < WP * CI * 2 / 16; i += 512)
            ((float4v*)(ldsA + 3 * WP * 128))[i] = z;
    }
    {
        const int sm  = wid & 3;
        const int sn  = wid >> 2;
        const int cpl = (lane >> 2) & 7;
        const int qlo = (lane & 3) + 4 * hi;
        const int ci0 = 2 * (cpl + 8 * sm);
        #pragma unroll
        for (int k = 0; k < 8; ++k) {
            const int r = k >> 1;
            const int Q = qlo + 8 * (sn + 2 * (k & 1));
            const int h = 2 * bx - 1 + r;
            if (h >= 0 && h < HH) {
                const float* p0 = x + (((size_t)b * CI + ci0) * HH + h) * WW + Q * 4;
                float4v a0 = *(const float4v*)p0;
                float4v a1 = *(const float4v*)(p0 + (size_t)HH * WW);
                #pragma unroll
                for (int e = 0; e < 4; ++e) {
                    const int wp   = Q * 4 + e + 1;
                    const int slot = (ci0 >> 3) ^ (wp & 7);
                    unsigned int pack;
                    asm("v_cvt_pk_bf16_f32 %0, %1, %2"
                        : "=v"(pack) : "v"(a0[e]), "v"(a1[e]));
                    *(unsigned int*)(ldsA + (size_t)(r * WP + wp) * 128
                                     + slot * 16 + (ci0 & 7) * 2) = pack;
                }
            }
        }
    }
    __syncthreads();

    int aaddr[6];
    #pragma unroll
    for (int dw = 0; dw < 3; ++dw) {
        const int key = (dw + l15) & 7;
        #pragma unroll
        for (int kc = 0; kc < 2; ++kc)
            aaddr[dw * 2 + kc] = (wm * WP + dw + cb + l15) * 128
                               + (((kc * 4 + quad) ^ key) << 4);
    }
    const unsigned short* wl = wt + (n0 + l15) * 32 + quad * 8;

    float4v acc[4][4];
    #pragma unroll
    for (int mt = 0; mt < 4; ++mt)
        #pragma unroll
        for (int nt = 0; nt < 4; ++nt)
            acc[mt][nt] = (float4v){0.f, 0.f, 0.f, 0.f};

    #pragma unroll
    for (int it = 0; it < 18; ++it) {
        const int tap = it >> 1;
        const int kc  = it & 1;
        const int dh  = tap / 3;
        const int dw  = tap % 3;

        const unsigned short* bp = wl + (size_t)it * (CO * 32);
        short8 bf[4];
        #pragma unroll
        for (int nt = 0; nt < 4; ++nt)
            bf[nt] = *(const short8*)(bp + nt * 16 * 32);

        const char* ab = ldsA + aaddr[dw * 2 + kc];
        short8 af[4];
        #pragma unroll
        for (int mt = 0; mt < 4; ++mt)
            af[mt] = *(const short8*)(ab + dh * (WP * 128) + mt * 2048);

        __builtin_amdgcn_s_setprio(1);
        #pragma unroll
        for (int mt = 0; mt < 4; ++mt)
            #pragma unroll
            for (int nt = 0; nt < 4; ++nt)
                acc[mt][nt] = __builtin_amdgcn_mfma_f32_16x16x32_bf16(
                    af[mt], bf[nt], acc[mt][nt], 0, 0, 0);
        __builtin_amdgcn_s_setprio(0);
    }

    float pm[4][4];
    #pragma unroll
    for (int mt = 0; mt < 4; ++mt)
        #pragma unroll
        for (int reg = 0; reg < 4; ++reg)
            pm[mt][reg] = fminf(fminf(acc[mt][0][reg], acc[mt][1][reg]),
                                fminf(acc[mt][2][reg], acc[mt][3][reg]));
    #pragma unroll
    for (int mt = 0; mt < 4; ++mt)
        #pragma unroll
        for (int reg = 0; reg < 4; ++reg) {
            pm[mt][reg] = fminror<0x128>(pm[mt][reg]);
            pm[mt][reg] = fminror<0x124>(pm[mt][reg]);
            pm[mt][reg] = fminror<0x122>(pm[mt][reg]);
            pm[mt][reg] = fminror<0x121>(pm[mt][reg]);
        }
    if (l15 == 0) {
        #pragma unroll
        for (int mt = 0; mt < 4; ++mt)
            #pragma unroll
            for (int reg = 0; reg < 4; ++reg)
                scratch[wn][wm][cb + mt * 16 + quad * 4 + reg] = pm[mt][reg];
    }
    __syncthreads();
    if (tid < 256) {
        int r = tid >> 7, c = tid & 127;
        float v = fminf(scratch[0][r][c], scratch[1][r][c]) * 2.0f;
        out[((size_t)b * HH + 2 * bx + r) * WW + c] = v;
    }
}

// ---------------- fallback (round-1 direct conv) ----------------

#define COT 16
__global__ __launch_bounds__(256) void conv_min_fallback(
    const float* __restrict__ x, const float* __restrict__ Wt,
    float* __restrict__ out)
{
    const int b  = blockIdx.y;
    const int h  = blockIdx.x * 2 + (threadIdx.x >> 7);
    const int w  = threadIdx.x & 127;
    const bool r0 = h > 0, r2 = h < HH - 1, c0 = w > 0, c2 = w < WW - 1;
    const float* xb = x + (size_t)b * CI * HH * WW;
    float vmin = 3.4e38f;
    for (int cb = 0; cb < CO; cb += COT) {
        float acc[COT];
        #pragma unroll
        for (int u = 0; u < COT; ++u) acc[u] = 0.0f;
        #pragma unroll 1
        for (int ci = 0; ci < CI; ++ci) {
            const float* xp = xb + ((size_t)ci * HH + h) * WW + w;
            float xv[9];
            xv[0] = (r0 && c0) ? xp[-WW - 1] : 0.0f;
            xv[1] =  r0        ? xp[-WW    ] : 0.0f;
            xv[2] = (r0 && c2) ? xp[-WW + 1] : 0.0f;
            xv[3] =        c0  ? xp[-1     ] : 0.0f;
            xv[4] =              xp[0      ];
            xv[5] =        c2  ? xp[1      ] : 0.0f;
            xv[6] = (r2 && c0) ? xp[ WW - 1] : 0.0f;
            xv[7] =  r2        ? xp[ WW    ] : 0.0f;
            xv[8] = (r2 && c2) ? xp[ WW + 1] : 0.0f;
            #pragma unroll
            for (int u = 0; u < COT; ++u) {
                const float* wp = Wt + ((size_t)(cb + u) * CI + ci) * 9;
                acc[u] += wp[0]*xv[0] + wp[1]*xv[1] + wp[2]*xv[2]
                        + wp[3]*xv[3] + wp[4]*xv[4] + wp[5]*xv[5]
                        + wp[6]*xv[6] + wp[7]*xv[7] + wp[8]*xv[8];
            }
        }
        #pragma unroll
        for (int u = 0; u < COT; ++u) vmin = fminf(vmin, acc[u]);
    }
    out[((size_t)b * HH + h) * WW + w] = vmin * 2.0f;
}

// ---------------- launch ----------------

extern "C" void kernel_launch(void* const* d_in, const int* in_sizes, int n_in,
                              void* d_out, int out_size, void* d_ws, size_t ws_size,
                              hipStream_t stream) {
    const float* x  = (const float*)d_in[0];   // (32,64,128,128)
    const float* Ws = (const float*)d_in[1];   // (128,64,3,3)
    float* out = (float*)d_out;                // (32,1,128,128)

    if (ws_size >= WT_BYTES + XT_BYTES) {
        unsigned short* wt  = (unsigned short*)d_ws;
        unsigned short* xtp = (unsigned short*)((char*)d_ws + WT_BYTES);
        prep_w<<<(9 * CO * CI + 255) / 256, 256, 0, stream>>>(Ws, wt);
        prep_x<<<dim3(XT_ROWS, 32), 256, 0, stream>>>(x, xtp);
        conv_main<<<256, 512, 0, stream>>>(xtp, wt, out);
    } else if (ws_size >= WT_BYTES) {
        unsigned short* wt = (unsigned short*)d_ws;
        prep_w<<<(9 * CO * CI + 255) / 256, 256, 0, stream>>>(Ws, wt);
        conv_fused<<<dim3(HH / 2, 32), 512, 0, stream>>>(x, wt, out);
    } else {
        dim3 grid(HH / 2, 32);
        conv_min_fallback<<<grid, 256, 0, stream>>>(x, Ws, out);
    }
}